// Round 17
// baseline (111.299 us; speedup 1.0000x reference)
//
#include <hip/hip_runtime.h>
#include <hip/hip_bf16.h>
#include <math.h>

#define MDIM 8192
#define NDIM 4096
#define KDIM 128
// grid: recon 2048 | S_m upper-tri 2080 | S_d upper-tri 528
#define G_SM0 2048
#define G_SD0 (2048 + 2080)
#define G_TOT (2048 + 2080 + 528)
#define G_PER_XCD (G_TOT / 8)   // 582, exact

typedef __bf16 bf16x8 __attribute__((ext_vector_type(8)));
typedef float f32x4 __attribute__((ext_vector_type(4)));

__device__ __forceinline__ unsigned short f32_to_bf16_rne(float f) {
  unsigned int u = __float_as_uint(f);
  u += 0x7fffu + ((u >> 16) & 1u);
  return (unsigned short)(u >> 16);
}

// Merged convert: blocks [0,256) handle U, [256,384) handle V.
__global__ void convert_merged(const float* __restrict__ U, const float* __restrict__ V,
                               unsigned short* __restrict__ Ub, unsigned short* __restrict__ Vb,
                               double* __restrict__ p_u, double* __restrict__ p_v) {
  const bool isV = blockIdx.x >= 256;
  const float4* X4 = (const float4*)(isV ? V : U);
  ushort4* Xb4 = (ushort4*)(isV ? Vb : Ub);
  const int n4 = isV ? (NDIM * KDIM / 4) : (MDIM * KDIM / 4);
  const int bid = isV ? (int)blockIdx.x - 256 : (int)blockIdx.x;
  const int nblk = isV ? 128 : 256;
  int i0 = bid * 256 + threadIdx.x;
  const int stride = nblk * 256;
  float s = 0.f;
  for (int i = i0; i < n4; i += stride) {
    float4 v = X4[i];
    s += v.x * v.x + v.y * v.y + v.z * v.z + v.w * v.w;
    ushort4 p;
    p.x = f32_to_bf16_rne(v.x);
    p.y = f32_to_bf16_rne(v.y);
    p.z = f32_to_bf16_rne(v.z);
    p.w = f32_to_bf16_rne(v.w);
    Xb4[i] = p;
  }
  for (int off = 32; off > 0; off >>= 1) s += __shfl_down(s, off, 64);
  __shared__ float sw[4];
  int lane = threadIdx.x & 63, wid = threadIdx.x >> 6;
  if (lane == 0) sw[wid] = s;
  __syncthreads();
  if (threadIdx.x == 0) {
    double r = (double)(sw[0] + sw[1] + sw[2] + sw[3]);
    if (isV) p_v[bid] = r; else p_u[bid] = r;
  }
}

// upper-triangle (incl. diagonal) row-major inversion: v -> (bi, bj), bi<=bj
__device__ __forceinline__ void tri_invert(int v, int n, int& bi, int& bj) {
  double dn = 2.0 * n + 1.0;
  int b = (int)((dn - sqrt(dn * dn - 8.0 * (double)v)) * 0.5);
  if (b < 0) b = 0;
  if (b > n - 1) b = n - 1;
  while (b + 1 <= n - 1 && ((b + 1) * n - ((b + 1) * b) / 2) <= v) ++b;
  while (b > 0 && (b * n - (b * (b - 1)) / 2) > v) --b;
  bi = b;
  bj = b + (v - (b * n - (b * (b - 1)) / 2));
}

// Fused products with symmetry exploitation (R16) + XCD-chunked block
// assignment (R17): hardware dispatches blockIdx round-robin over the 8
// XCDs, so the bijective remap v = (g&7)*582 + (g>>3) hands each XCD a
// CONTIGUOUS row-major run of tiles — the shared X panel and the Y panel
// row stay hot in that XCD's private 4MB L2 instead of bouncing through
// LLC, shortening the per-block stage-wait (the only serialized phase).
//   v in [0,2048):        recon tile (Ub Vb^T vs A), normal path
//   v in [2048,4128):     S_m upper-tri (bi<=bj); bi<bj = dual path
//   v in [4128,4656):     S_d upper-tri, dual path
__global__ __launch_bounds__(256, 2) void fused_all(
    const unsigned short* __restrict__ Ub,  // [M][128] bf16 bits
    const unsigned short* __restrict__ Vb,  // [N][128] bf16 bits
    const float* __restrict__ A,
    const float* __restrict__ S_m,
    const float* __restrict__ S_d,
    double* __restrict__ partial) {
  __shared__ float LDSf[16384];  // 64KB: panels (X:0-32KB, Y:32-64KB), then P / P^T
  char* LDSc = (char*)LDSf;

  // XCD-chunked bijective remap (G_TOT % 8 == 0)
  const int g = ((int)blockIdx.x & 7) * G_PER_XCD + ((int)blockIdx.x >> 3);

  const unsigned short* Xb;
  const unsigned short* Yb;
  const float* T;
  int ldT, brow, bcol;
  bool dual = false;
  if (g < G_SM0) {
    Xb = Ub; Yb = Vb; T = A; ldT = NDIM;
    brow = (g >> 5) * 128; bcol = (g & 31) * 128;
  } else if (g < G_SD0) {
    int bi, bj;
    tri_invert(g - G_SM0, 64, bi, bj);
    Xb = Ub; Yb = Ub; T = S_m; ldT = MDIM;
    brow = bi * 128; bcol = bj * 128; dual = (bj > bi);
  } else {
    int bi, bj;
    tri_invert(g - G_SD0, 32, bi, bj);
    Xb = Vb; Yb = Vb; T = S_d; ldT = NDIM;
    brow = bi * 128; bcol = bj * 128; dual = (bj > bi);
  }

  const int tid = threadIdx.x;
  const int lane = tid & 63;
  const int wid = tid >> 6;
  const int wr = wid >> 1, wc = wid & 1;
  const int l15 = lane & 15;
  const int lg = lane >> 4;

  // ---- 1) stage X,Y panels to LDS: wave-linear dest, chunk-swizzled source ----
  {
    const int ro = lane >> 4;       // row within 4-row group
    const int j = lane & 15;        // 16B chunk within row
#pragma unroll
    for (int i = 0; i < 8; ++i) {
      const int rl = wid * 32 + i * 4 + ro;
      const unsigned short* gp = Xb + (size_t)(brow + rl) * KDIM + ((j ^ (rl & 7)) << 3);
      __builtin_amdgcn_global_load_lds(
          (const __attribute__((address_space(1))) void*)gp,
          (__attribute__((address_space(3))) void*)(LDSc + (wid * 32 + i * 4) * 256), 16, 0, 0);
    }
#pragma unroll
    for (int i = 0; i < 8; ++i) {
      const int rl = wid * 32 + i * 4 + ro;
      const unsigned short* gp = Yb + (size_t)(bcol + rl) * KDIM + ((j ^ (rl & 7)) << 3);
      __builtin_amdgcn_global_load_lds(
          (const __attribute__((address_space(1))) void*)gp,
          (__attribute__((address_space(3))) void*)(LDSc + 32768 + (wid * 32 + i * 4) * 256), 16, 0, 0);
    }
  }
  __builtin_amdgcn_sched_barrier(0);

  // ---- 2) T tile (bi,bj) -> registers, wave-contiguous, NON-TEMPORAL ----
  const int ldT4 = ldT >> 2;
  const f32x4* Tb = (const f32x4*)T + (size_t)brow * ldT4 + (bcol >> 2);
  const int tr = tid >> 5, tc = tid & 31;
  f32x4 t[16];
#pragma unroll
  for (int it = 0; it < 16; ++it)
    t[it] = __builtin_nontemporal_load(&Tb[(size_t)(it * 8 + tr) * ldT4 + tc]);
  __builtin_amdgcn_sched_barrier(0);

  // ---- panels done (ALL 16 T loads still in flight), all waves synced ----
  asm volatile("s_waitcnt vmcnt(16)" ::: "memory");
  __builtin_amdgcn_sched_barrier(0);
  __builtin_amdgcn_s_barrier();

  // ---- 3) MFMA phase: operands from LDS (lgkmcnt only — T never drained) ----
  f32x4 acc[4][4] = {};  // acc[p][q][reg] = P[wr*64+q*16+l15][wc*64+p*16+lg*4+reg]
#pragma unroll
  for (int kk = 0; kk < 4; ++kk) {
    const int c = kk * 4 + lg;
    bf16x8 y[4], x[4];
#pragma unroll
    for (int p = 0; p < 4; ++p) {
      const int rl = wc * 64 + p * 16 + l15;
      y[p] = *(const bf16x8*)(LDSc + 32768 + rl * 256 + ((c ^ (rl & 7)) << 4));
    }
#pragma unroll
    for (int q = 0; q < 4; ++q) {
      const int rl = wr * 64 + q * 16 + l15;
      x[q] = *(const bf16x8*)(LDSc + rl * 256 + ((c ^ (rl & 7)) << 4));
    }
#pragma unroll
    for (int p = 0; p < 4; ++p)
#pragma unroll
      for (int q = 0; q < 4; ++q)
        acc[p][q] = __builtin_amdgcn_mfma_f32_16x16x32_bf16(y[p], x[q], acc[p][q], 0, 0, 0);
  }

  // ---- 3b) dual blocks: issue transposed-tile T2 loads now (latency hides
  //          under P-write + compare1) ----
  f32x4 t2[16];
  if (dual) {
    const f32x4* Tb2 = (const f32x4*)T + (size_t)bcol * ldT4 + (brow >> 2);
#pragma unroll
    for (int it = 0; it < 16; ++it)
      t2[it] = __builtin_nontemporal_load(&Tb2[(size_t)(it * 8 + tr) * ldT4 + tc]);
  }

  // ---- 4) panels dead; overlay P into the same LDS (swizzled f32x4) ----
  __syncthreads();
#pragma unroll
  for (int q = 0; q < 4; ++q) {
    const int rp = wr * 64 + q * 16 + l15;
#pragma unroll
    for (int p = 0; p < 4; ++p) {
      const int cw = wc * 16 + p * 4 + lg;
      *(f32x4*)(LDSc + rp * 512 + ((cw ^ (rp & 7)) << 4)) = acc[p][q];
    }
  }
  __syncthreads();

  // ---- 5) compare1: wave-contiguous LDS reads vs register T ----
  float s = 0.f;
#pragma unroll
  for (int it = 0; it < 16; ++it) {
    const int r = it * 8 + tr;
    const f32x4 pv = *(const f32x4*)(LDSc + r * 512 + ((tc ^ (r & 7)) << 4));
    const f32x4 d = pv - t[it];
    s += d[0] * d[0] + d[1] * d[1] + d[2] * d[2] + d[3] * d[3];
  }

  // ---- 6) dual: overlay P^T (scalar dwords, same involution swizzle —
  //          exactly 2-way banked = free) and run the identical compare vs T2
  if (dual) {
    __syncthreads();
#pragma unroll
    for (int p = 0; p < 4; ++p) {
#pragma unroll
      for (int q = 0; q < 4; ++q) {
        const int ptc = wr * 64 + q * 16 + l15;  // P^T col = P row
#pragma unroll
        for (int j = 0; j < 4; ++j) {
          const int ptr_ = wc * 64 + p * 16 + lg * 4 + j;  // P^T row = P col
          *(float*)(LDSc + ptr_ * 512 + ((((ptc >> 2) ^ (ptr_ & 7))) << 4) + ((ptc & 3) << 2)) =
              acc[p][q][j];
        }
      }
    }
    __syncthreads();
#pragma unroll
    for (int it = 0; it < 16; ++it) {
      const int r = it * 8 + tr;
      const f32x4 pv = *(const f32x4*)(LDSc + r * 512 + ((tc ^ (r & 7)) << 4));
      const f32x4 d = pv - t2[it];
      s += d[0] * d[0] + d[1] * d[1] + d[2] * d[2] + d[3] * d[3];
    }
  }

  // deterministic block reduction
  for (int off = 32; off > 0; off >>= 1) s += __shfl_down(s, off, 64);
  __shared__ float swred[4];
  if (lane == 0) swred[wid] = s;
  __syncthreads();
  if (tid == 0)
    partial[g] = (double)(swred[0] + swred[1] + swred[2] + swred[3]);
}

// Deterministic final reduction of all partial arrays + scalar combine.
__global__ void finalize_kernel(const double* __restrict__ pr, int nr,
                                const double* __restrict__ psm, int nsm,
                                const double* __restrict__ psd, int nsd,
                                const double* __restrict__ pu, int nu,
                                const double* __restrict__ pv, int nv,
                                float* __restrict__ out) {
  __shared__ double sh[256];
  double sums[5];
  const double* ps[5] = {pr, psm, psd, pu, pv};
  int ns[5] = {nr, nsm, nsd, nu, nv};
  for (int q = 0; q < 5; ++q) {
    double s = 0.0;
    for (int i = threadIdx.x; i < ns[q]; i += 256) s += ps[q][i];
    sh[threadIdx.x] = s;
    __syncthreads();
    for (int k = 128; k > 0; k >>= 1) {
      if (threadIdx.x < k) sh[threadIdx.x] += sh[threadIdx.x + k];
      __syncthreads();
    }
    sums[q] = sh[0];
    __syncthreads();
  }
  if (threadIdx.x == 0) {
    double recon = sums[0] / ((double)MDIM * (double)NDIM);
    double res = recon + 0.01 * (sqrt(sums[3]) + sqrt(sums[4]) + sqrt(sums[1]) + sqrt(sums[2]));
    out[0] = (float)res;
  }
}

extern "C" void kernel_launch(void* const* d_in, const int* in_sizes, int n_in,
                              void* d_out, int out_size, void* d_ws, size_t ws_size,
                              hipStream_t stream) {
  const float* A   = (const float*)d_in[0];  // [M][N]
  const float* S_m = (const float*)d_in[1];  // [M][M]
  const float* S_d = (const float*)d_in[2];  // [N][N]
  const float* U   = (const float*)d_in[3];  // [M][K]
  const float* V   = (const float*)d_in[4];  // [N][K]

  char* ws = (char*)d_ws;
  unsigned short* Ub = (unsigned short*)ws;                             // 2 MB
  unsigned short* Vb = (unsigned short*)(ws + (size_t)2 * 1024 * 1024); // 1 MB
  double* pd = (double*)(ws + (size_t)3 * 1024 * 1024);
  double* p_all = pd;             // G_TOT: [0,2048) recon | [2048,4128) S_m | [4128,4656) S_d
  double* p_u   = p_all + G_TOT;  // 256
  double* p_v   = p_u + 256;      // 128

  convert_merged<<<384, 256, 0, stream>>>(U, V, Ub, Vb, p_u, p_v);

  fused_all<<<G_TOT, 256, 0, stream>>>(Ub, Vb, A, S_m, S_d, p_all);

  finalize_kernel<<<1, 256, 0, stream>>>(p_all, 2048, p_all + 2048, 2080, p_all + G_SD0, 528,
                                         p_u, 256, p_v, 128, (float*)d_out);
}

// Round 18
// 97.235 us; speedup vs baseline: 1.1446x; 1.1446x over previous
//
#include <hip/hip_runtime.h>
#include <hip/hip_bf16.h>
#include <math.h>

#define MDIM 8192
#define NDIM 4096
#define KDIM 128
// grid: recon 2048 | S_m upper-tri 2080 | S_d upper-tri 528
#define G_SM0 2048
#define G_SD0 (2048 + 2080)
#define G_TOT (2048 + 2080 + 528)

typedef __bf16 bf16x8 __attribute__((ext_vector_type(8)));
typedef float f32x4 __attribute__((ext_vector_type(4)));

__device__ __forceinline__ unsigned short f32_to_bf16_rne(float f) {
  unsigned int u = __float_as_uint(f);
  u += 0x7fffu + ((u >> 16) & 1u);
  return (unsigned short)(u >> 16);
}

// Merged convert: blocks [0,256) handle U, [256,384) handle V.
__global__ void convert_merged(const float* __restrict__ U, const float* __restrict__ V,
                               unsigned short* __restrict__ Ub, unsigned short* __restrict__ Vb,
                               double* __restrict__ p_u, double* __restrict__ p_v) {
  const bool isV = blockIdx.x >= 256;
  const float4* X4 = (const float4*)(isV ? V : U);
  ushort4* Xb4 = (ushort4*)(isV ? Vb : Ub);
  const int n4 = isV ? (NDIM * KDIM / 4) : (MDIM * KDIM / 4);
  const int bid = isV ? (int)blockIdx.x - 256 : (int)blockIdx.x;
  const int nblk = isV ? 128 : 256;
  int i0 = bid * 256 + threadIdx.x;
  const int stride = nblk * 256;
  float s = 0.f;
  for (int i = i0; i < n4; i += stride) {
    float4 v = X4[i];
    s += v.x * v.x + v.y * v.y + v.z * v.z + v.w * v.w;
    ushort4 p;
    p.x = f32_to_bf16_rne(v.x);
    p.y = f32_to_bf16_rne(v.y);
    p.z = f32_to_bf16_rne(v.z);
    p.w = f32_to_bf16_rne(v.w);
    Xb4[i] = p;
  }
  for (int off = 32; off > 0; off >>= 1) s += __shfl_down(s, off, 64);
  __shared__ float sw[4];
  int lane = threadIdx.x & 63, wid = threadIdx.x >> 6;
  if (lane == 0) sw[wid] = s;
  __syncthreads();
  if (threadIdx.x == 0) {
    double r = (double)(sw[0] + sw[1] + sw[2] + sw[3]);
    if (isV) p_v[bid] = r; else p_u[bid] = r;
  }
}

// upper-triangle (incl. diagonal) row-major inversion: v -> (bi, bj), bi<=bj
__device__ __forceinline__ void tri_invert(int v, int n, int& bi, int& bj) {
  double dn = 2.0 * n + 1.0;
  int b = (int)((dn - sqrt(dn * dn - 8.0 * (double)v)) * 0.5);
  if (b < 0) b = 0;
  if (b > n - 1) b = n - 1;
  while (b + 1 <= n - 1 && ((b + 1) * n - ((b + 1) * b) / 2) <= v) ++b;
  while (b > 0 && (b * n - (b * (b - 1)) / 2) > v) --b;
  bi = b;
  bj = b + (v - (b * n - (b * (b - 1)) / 2));
}

// FINAL (R16 structure): fused products with symmetry exploitation.
//   g in [0,2048):        recon tile (Ub Vb^T vs A), normal path
//   g in [2048,4128):     S_m upper-tri tile (bi<=bj); bi<bj = dual path
//                         (compare P vs S_m[bi,bj] AND P^T vs S_m[bj,bi])
//   g in [4128,4656):     S_d upper-tri, dual path
// Body (each element A/B-validated over 17 rounds):
//  - all global accesses wave-contiguous full 128B lines (R9: +40%)
//  - panels via global_load_lds, XOR-swizzled source involution (rule #21)
//  - T non-temporal to registers (full-line once-read stream; R13)
//  - counted vmcnt(16): completes exactly the 12 panel DMAs, leaves all 16
//    T loads in flight across MFMA+P-write (R13)
//  - MFMA operands from LDS (lgkmcnt — operand waits never drain T queue)
//  - P (and P^T for dual) redistributed through dead-panel LDS, 2-way-max
//    banked, compare is conflict-free f32x4 vs register T (R9/R16)
//  - natural dispatch order (R17: XCD-chunked remap regresses -14%)
//  - NO grid-wide fence/atomic finalize (R14: __threadfence costs 4x)
__global__ __launch_bounds__(256, 2) void fused_all(
    const unsigned short* __restrict__ Ub,  // [M][128] bf16 bits
    const unsigned short* __restrict__ Vb,  // [N][128] bf16 bits
    const float* __restrict__ A,
    const float* __restrict__ S_m,
    const float* __restrict__ S_d,
    double* __restrict__ partial) {
  __shared__ float LDSf[16384];  // 64KB: panels (X:0-32KB, Y:32-64KB), then P / P^T
  char* LDSc = (char*)LDSf;

  const int g = blockIdx.x;
  const unsigned short* Xb;
  const unsigned short* Yb;
  const float* T;
  int ldT, brow, bcol;
  bool dual = false;
  if (g < G_SM0) {
    Xb = Ub; Yb = Vb; T = A; ldT = NDIM;
    brow = (g >> 5) * 128; bcol = (g & 31) * 128;
  } else if (g < G_SD0) {
    int bi, bj;
    tri_invert(g - G_SM0, 64, bi, bj);
    Xb = Ub; Yb = Ub; T = S_m; ldT = MDIM;
    brow = bi * 128; bcol = bj * 128; dual = (bj > bi);
  } else {
    int bi, bj;
    tri_invert(g - G_SD0, 32, bi, bj);
    Xb = Vb; Yb = Vb; T = S_d; ldT = NDIM;
    brow = bi * 128; bcol = bj * 128; dual = (bj > bi);
  }

  const int tid = threadIdx.x;
  const int lane = tid & 63;
  const int wid = tid >> 6;
  const int wr = wid >> 1, wc = wid & 1;
  const int l15 = lane & 15;
  const int lg = lane >> 4;

  // ---- 1) stage X,Y panels to LDS: wave-linear dest, chunk-swizzled source ----
  {
    const int ro = lane >> 4;       // row within 4-row group
    const int j = lane & 15;        // 16B chunk within row
#pragma unroll
    for (int i = 0; i < 8; ++i) {
      const int rl = wid * 32 + i * 4 + ro;
      const unsigned short* gp = Xb + (size_t)(brow + rl) * KDIM + ((j ^ (rl & 7)) << 3);
      __builtin_amdgcn_global_load_lds(
          (const __attribute__((address_space(1))) void*)gp,
          (__attribute__((address_space(3))) void*)(LDSc + (wid * 32 + i * 4) * 256), 16, 0, 0);
    }
#pragma unroll
    for (int i = 0; i < 8; ++i) {
      const int rl = wid * 32 + i * 4 + ro;
      const unsigned short* gp = Yb + (size_t)(bcol + rl) * KDIM + ((j ^ (rl & 7)) << 3);
      __builtin_amdgcn_global_load_lds(
          (const __attribute__((address_space(1))) void*)gp,
          (__attribute__((address_space(3))) void*)(LDSc + 32768 + (wid * 32 + i * 4) * 256), 16, 0, 0);
    }
  }
  __builtin_amdgcn_sched_barrier(0);

  // ---- 2) T tile (bi,bj) -> registers, wave-contiguous, NON-TEMPORAL ----
  const int ldT4 = ldT >> 2;
  const f32x4* Tb = (const f32x4*)T + (size_t)brow * ldT4 + (bcol >> 2);
  const int tr = tid >> 5, tc = tid & 31;
  f32x4 t[16];
#pragma unroll
  for (int it = 0; it < 16; ++it)
    t[it] = __builtin_nontemporal_load(&Tb[(size_t)(it * 8 + tr) * ldT4 + tc]);
  __builtin_amdgcn_sched_barrier(0);

  // ---- panels done (ALL 16 T loads still in flight), all waves synced ----
  asm volatile("s_waitcnt vmcnt(16)" ::: "memory");
  __builtin_amdgcn_sched_barrier(0);
  __builtin_amdgcn_s_barrier();

  // ---- 3) MFMA phase: operands from LDS (lgkmcnt only — T never drained) ----
  f32x4 acc[4][4] = {};  // acc[p][q][reg] = P[wr*64+q*16+l15][wc*64+p*16+lg*4+reg]
#pragma unroll
  for (int kk = 0; kk < 4; ++kk) {
    const int c = kk * 4 + lg;
    bf16x8 y[4], x[4];
#pragma unroll
    for (int p = 0; p < 4; ++p) {
      const int rl = wc * 64 + p * 16 + l15;
      y[p] = *(const bf16x8*)(LDSc + 32768 + rl * 256 + ((c ^ (rl & 7)) << 4));
    }
#pragma unroll
    for (int q = 0; q < 4; ++q) {
      const int rl = wr * 64 + q * 16 + l15;
      x[q] = *(const bf16x8*)(LDSc + rl * 256 + ((c ^ (rl & 7)) << 4));
    }
#pragma unroll
    for (int p = 0; p < 4; ++p)
#pragma unroll
      for (int q = 0; q < 4; ++q)
        acc[p][q] = __builtin_amdgcn_mfma_f32_16x16x32_bf16(y[p], x[q], acc[p][q], 0, 0, 0);
  }

  // ---- 3b) dual blocks: issue transposed-tile T2 loads now (latency hides
  //          under P-write + compare1) ----
  f32x4 t2[16];
  if (dual) {
    const f32x4* Tb2 = (const f32x4*)T + (size_t)bcol * ldT4 + (brow >> 2);
#pragma unroll
    for (int it = 0; it < 16; ++it)
      t2[it] = __builtin_nontemporal_load(&Tb2[(size_t)(it * 8 + tr) * ldT4 + tc]);
  }

  // ---- 4) panels dead; overlay P into the same LDS (swizzled f32x4) ----
  __syncthreads();
#pragma unroll
  for (int q = 0; q < 4; ++q) {
    const int rp = wr * 64 + q * 16 + l15;
#pragma unroll
    for (int p = 0; p < 4; ++p) {
      const int cw = wc * 16 + p * 4 + lg;
      *(f32x4*)(LDSc + rp * 512 + ((cw ^ (rp & 7)) << 4)) = acc[p][q];
    }
  }
  __syncthreads();

  // ---- 5) compare1: wave-contiguous LDS reads vs register T ----
  float s = 0.f;
#pragma unroll
  for (int it = 0; it < 16; ++it) {
    const int r = it * 8 + tr;
    const f32x4 pv = *(const f32x4*)(LDSc + r * 512 + ((tc ^ (r & 7)) << 4));
    const f32x4 d = pv - t[it];
    s += d[0] * d[0] + d[1] * d[1] + d[2] * d[2] + d[3] * d[3];
  }

  // ---- 6) dual: overlay P^T (scalar dwords, same involution swizzle —
  //          exactly 2-way banked = free) and run the identical compare vs T2
  if (dual) {
    __syncthreads();
#pragma unroll
    for (int p = 0; p < 4; ++p) {
#pragma unroll
      for (int q = 0; q < 4; ++q) {
        const int ptc = wr * 64 + q * 16 + l15;  // P^T col = P row
#pragma unroll
        for (int j = 0; j < 4; ++j) {
          const int ptr_ = wc * 64 + p * 16 + lg * 4 + j;  // P^T row = P col
          *(float*)(LDSc + ptr_ * 512 + ((((ptc >> 2) ^ (ptr_ & 7))) << 4) + ((ptc & 3) << 2)) =
              acc[p][q][j];
        }
      }
    }
    __syncthreads();
#pragma unroll
    for (int it = 0; it < 16; ++it) {
      const int r = it * 8 + tr;
      const f32x4 pv = *(const f32x4*)(LDSc + r * 512 + ((tc ^ (r & 7)) << 4));
      const f32x4 d = pv - t2[it];
      s += d[0] * d[0] + d[1] * d[1] + d[2] * d[2] + d[3] * d[3];
    }
  }

  // deterministic block reduction
  for (int off = 32; off > 0; off >>= 1) s += __shfl_down(s, off, 64);
  __shared__ float swred[4];
  if (lane == 0) swred[wid] = s;
  __syncthreads();
  if (tid == 0)
    partial[g] = (double)(swred[0] + swred[1] + swred[2] + swred[3]);
}

// Deterministic final reduction of all partial arrays + scalar combine.
__global__ void finalize_kernel(const double* __restrict__ pr, int nr,
                                const double* __restrict__ psm, int nsm,
                                const double* __restrict__ psd, int nsd,
                                const double* __restrict__ pu, int nu,
                                const double* __restrict__ pv, int nv,
                                float* __restrict__ out) {
  __shared__ double sh[256];
  double sums[5];
  const double* ps[5] = {pr, psm, psd, pu, pv};
  int ns[5] = {nr, nsm, nsd, nu, nv};
  for (int q = 0; q < 5; ++q) {
    double s = 0.0;
    for (int i = threadIdx.x; i < ns[q]; i += 256) s += ps[q][i];
    sh[threadIdx.x] = s;
    __syncthreads();
    for (int k = 128; k > 0; k >>= 1) {
      if (threadIdx.x < k) sh[threadIdx.x] += sh[threadIdx.x + k];
      __syncthreads();
    }
    sums[q] = sh[0];
    __syncthreads();
  }
  if (threadIdx.x == 0) {
    double recon = sums[0] / ((double)MDIM * (double)NDIM);
    double res = recon + 0.01 * (sqrt(sums[3]) + sqrt(sums[4]) + sqrt(sums[1]) + sqrt(sums[2]));
    out[0] = (float)res;
  }
}

extern "C" void kernel_launch(void* const* d_in, const int* in_sizes, int n_in,
                              void* d_out, int out_size, void* d_ws, size_t ws_size,
                              hipStream_t stream) {
  const float* A   = (const float*)d_in[0];  // [M][N]
  const float* S_m = (const float*)d_in[1];  // [M][M]
  const float* S_d = (const float*)d_in[2];  // [N][N]
  const float* U   = (const float*)d_in[3];  // [M][K]
  const float* V   = (const float*)d_in[4];  // [N][K]

  char* ws = (char*)d_ws;
  unsigned short* Ub = (unsigned short*)ws;                             // 2 MB
  unsigned short* Vb = (unsigned short*)(ws + (size_t)2 * 1024 * 1024); // 1 MB
  double* pd = (double*)(ws + (size_t)3 * 1024 * 1024);
  double* p_all = pd;             // G_TOT: [0,2048) recon | [2048,4128) S_m | [4128,4656) S_d
  double* p_u   = p_all + G_TOT;  // 256
  double* p_v   = p_u + 256;      // 128

  convert_merged<<<384, 256, 0, stream>>>(U, V, Ub, Vb, p_u, p_v);

  fused_all<<<G_TOT, 256, 0, stream>>>(Ub, Vb, A, S_m, S_d, p_all);

  finalize_kernel<<<1, 256, 0, stream>>>(p_all, 2048, p_all + 2048, 2080, p_all + G_SD0, 528,
                                         p_u, 256, p_v, 128, (float*)d_out);
}